// Round 1
// baseline (1335.651 us; speedup 1.0000x reference)
//
#include <hip/hip_runtime.h>
#include <hip/hip_bf16.h>
#include <stdint.h>

// Problem constants (B=1024, N=68, C=768, H=12, hd=64)
static constexpr int BATCH = 1024;
static constexpr int NTOK  = 68;
static constexpr int CDIM  = 768;
static constexpr int NHEAD = 12;
static constexpr int M_ROWS = BATCH * NTOK;      // 69632 = 544*128
static constexpr int KDIM   = CDIM;              // 768

typedef float  f32x4  __attribute__((ext_vector_type(4)));
typedef __bf16 bf16x8 __attribute__((ext_vector_type(8)));

__device__ __forceinline__ f32x4 mfma16(bf16x8 a, bf16x8 b, f32x4 c) {
  return __builtin_amdgcn_mfma_f32_16x16x32_bf16(a, b, c, 0, 0, 0);
}

__device__ __forceinline__ void async_ld16(void* lds, const void* g) {
  __builtin_amdgcn_global_load_lds((const __attribute__((address_space(1))) void*)g,
                                   (__attribute__((address_space(3))) void*)lds,
                                   16, 0, 0);
}

__device__ __forceinline__ void store4bf16(__hip_bfloat16* dst, f32x4 v) {
  __hip_bfloat16 tmp[4];
  tmp[0] = __float2bfloat16(v[0]);
  tmp[1] = __float2bfloat16(v[1]);
  tmp[2] = __float2bfloat16(v[2]);
  tmp[3] = __float2bfloat16(v[3]);
  *(uint2*)dst = *(const uint2*)tmp;
}

// ---------------- prep: f32 -> bf16 weight convert ----------------
__global__ __launch_bounds__(256) void cvt_bf16(const float* __restrict__ src,
                                                __hip_bfloat16* __restrict__ dst, int n4) {
  int i = blockIdx.x * 256 + threadIdx.x;
  if (i >= n4) return;
  f32x4 v = ((const f32x4*)src)[i];
  store4bf16(dst + (size_t)i * 4, v);
}

// ---------------- prep: xb = bf16(x + pe_crop) ----------------
// one float4 per thread over 69632*192 float4s
__global__ __launch_bounds__(256) void prep_x(const float* __restrict__ x,
                                              const float* __restrict__ pe,
                                              __hip_bfloat16* __restrict__ xb) {
  int i = blockIdx.x * 256 + threadIdx.x;   // < 13,369,344 (exact grid)
  int m  = i / 192;
  int c4 = i - m * 192;
  int n  = m % 68;
  f32x4 v = ((const f32x4*)x)[i];
  if (n >= 4) {
    // pe row = 32 + (n-4) = n + 28
    f32x4 p = ((const f32x4*)pe)[(n + 28) * 192 + c4];
    v[0] += p[0]; v[1] += p[1]; v[2] += p[2]; v[3] += p[3];
  }
  store4bf16(xb + (size_t)i * 4, v);
}

// ---------------- GEMM: C[m,j] = sum_k A[m,k]*B[j,k] + bias[j] ----------------
// 128x128 tile, BK=64, 4 waves (each 64x64 = 4x4 frags of 16x16x32 bf16 MFMA).
// LDS XOR-swizzled (byte ^= (row&7)<<4) with pre-swizzled global source for
// global_load_lds (linear dest). EPI=0: scatter to q/k/v bf16 (+0.125 on q);
// EPI=1: f32 out + bias.
template<int EPI>
__global__ __launch_bounds__(256)
void gemm_bt(const __hip_bfloat16* __restrict__ A,
             const __hip_bfloat16* __restrict__ Bm,
             const float* __restrict__ bias,
             __hip_bfloat16* __restrict__ qo,
             __hip_bfloat16* __restrict__ ko,
             __hip_bfloat16* __restrict__ vo,
             float* __restrict__ out,
             int K) {
  __shared__ __align__(16) char lds[32768];
  char* lA = lds;
  char* lB = lds + 16384;

  const int tid  = threadIdx.x;
  const int w    = tid >> 6;
  const int lane = tid & 63;
  const int m0 = blockIdx.y * 128;
  const int n0 = blockIdx.x * 128;
  const int lrow = lane >> 3, slot = lane & 7;
  const size_t ldb = (size_t)K * 2;  // row stride bytes

  f32x4 acc[4][4];
#pragma unroll
  for (int i = 0; i < 4; ++i)
#pragma unroll
    for (int j = 0; j < 4; ++j) acc[i][j] = (f32x4){0.f, 0.f, 0.f, 0.f};

  const int wr = w >> 1, wc = w & 1;
  const int fr = lane & 15, fkb = (lane >> 4) << 4;

  const char* Ab = (const char*)A;
  const char* Bb = (const char*)Bm;

  for (int kt = 0; kt < K; kt += 64) {
#pragma unroll
    for (int c2 = 0; c2 < 4; ++c2) {
      int rb = c2 * 32 + w * 8;       // 8 rows per wave-call
      int r  = rb + lrow;
      int sk = (slot ^ (r & 7)) << 4; // pre-swizzled source k-slot
      async_ld16(lA + rb * 128, Ab + (size_t)(m0 + r) * ldb + (size_t)kt * 2 + sk);
      async_ld16(lB + rb * 128, Bb + (size_t)(n0 + r) * ldb + (size_t)kt * 2 + sk);
    }
    __syncthreads();
#pragma unroll
    for (int k0 = 0; k0 < 2; ++k0) {
      bf16x8 af[4], bfv[4];
#pragma unroll
      for (int i = 0; i < 4; ++i) {
        int ra = wr * 64 + i * 16 + fr;
        af[i] = *(const bf16x8*)(lA + ra * 128 + ((k0 * 64 + fkb) ^ ((ra & 7) << 4)));
        int rbB = wc * 64 + i * 16 + fr;
        bfv[i] = *(const bf16x8*)(lB + rbB * 128 + ((k0 * 64 + fkb) ^ ((rbB & 7) << 4)));
      }
#pragma unroll
      for (int i = 0; i < 4; ++i)
#pragma unroll
        for (int j = 0; j < 4; ++j)
          acc[i][j] = mfma16(af[i], bfv[j], acc[i][j]);
    }
    __syncthreads();
  }

  // epilogue: C/D layout col = lane&15, row = (lane>>4)*4 + r
#pragma unroll
  for (int i = 0; i < 4; ++i) {
#pragma unroll
    for (int j = 0; j < 4; ++j) {
#pragma unroll
      for (int r = 0; r < 4; ++r) {
        int m  = m0 + wr * 64 + i * 16 + ((lane >> 4) << 2) + r;
        int jj = n0 + wc * 64 + j * 16 + (lane & 15);
        float val = acc[i][j][r] + bias[jj];
        if (EPI == 0) {
          int which = (jj >= 1536) ? 2 : (jj >= 768 ? 1 : 0);
          int jl = jj - which * 768;
          int h = jl >> 6, d = jl & 63;
          if (which == 0) val *= 0.125f;  // hd^-0.5
          int bb = m / 68, n = m - bb * 68;
          __hip_bfloat16* dst = (which == 0) ? qo : (which == 1 ? ko : vo);
          dst[((size_t)(bb * 12 + h) * 68 + n) * 64 + d] = __float2bfloat16(val);
        } else {
          out[(size_t)m * 768 + jj] = val;
        }
      }
    }
  }
}

// ---------------- attention: one block per (b,h) ----------------
// LDS: QP region (Q[80][64] bf16 then P[80][stride192] bf16), K[80][64] bf16,
// Vt[64][stride192] bf16 (V transposed), S[80][81] f32.
__global__ __launch_bounds__(256)
void attn(const __hip_bfloat16* __restrict__ q,
          const __hip_bfloat16* __restrict__ kk,
          const __hip_bfloat16* __restrict__ vv,
          const float* __restrict__ mask,
          __hip_bfloat16* __restrict__ ao) {
  __shared__ __align__(16) char sm[63808];
  char*  Pq = sm;                    // 0..15360
  char*  Kl = sm + 15360;            // 10240
  char*  Vt = sm + 25600;            // 12288
  float* S  = (float*)(sm + 37888);  // 80*81*4 = 25920

  const int tid  = threadIdx.x;
  const int w    = tid >> 6;
  const int lane = tid & 63;
  const int bh = blockIdx.x, b = bh / 12, h = bh - b * 12;

  // zero all LDS (kills garbage in pad rows/cols)
  for (int e = tid; e < 15952; e += 256) ((uint32_t*)sm)[e] = 0u;
  __syncthreads();

  const __hip_bfloat16* qg = q  + (size_t)bh * 4352;
  const __hip_bfloat16* kg = kk + (size_t)bh * 4352;
  const __hip_bfloat16* vg = vv + (size_t)bh * 4352;

  // stage Q, K (row stride 128B, 3-bit XOR swizzle)
  for (int e = tid; e < 544; e += 256) {
    int row = e >> 3, slot = e & 7;
    int off = row * 128 + (((slot << 4)) ^ ((row & 7) << 4));
    *(bf16x8*)(Pq + off) = *(const bf16x8*)(qg + e * 8);
    *(bf16x8*)(Kl + off) = *(const bf16x8*)(kg + e * 8);
  }
  // stage V transposed: Vt[d][j], row stride 192B, 2-bit XOR swizzle
  for (int e = tid; e < 544; e += 256) {
    int j = e >> 3, d8 = e & 7;
    bf16x8 vx = *(const bf16x8*)(vg + e * 8);
#pragma unroll
    for (int u = 0; u < 8; ++u) {
      int d = d8 * 8 + u;
      *(__bf16*)(Vt + d * 192 + ((2 * j) ^ ((d & 3) << 4))) = vx[u];
    }
  }
  __syncthreads();

  const int fr = lane & 15, fkb = (lane >> 4) << 4;

  // S = Q @ K^T over 5x5 tiles of 16x16 (K=64 -> 2 steps)
  for (int t = w; t < 25; t += 4) {
    int ti = t / 5, tj = t - ti * 5;
    f32x4 a4 = (f32x4){0.f, 0.f, 0.f, 0.f};
#pragma unroll
    for (int k0 = 0; k0 < 2; ++k0) {
      int ra = ti * 16 + fr;
      bf16x8 af = *(const bf16x8*)(Pq + ra * 128 + ((k0 * 64 + fkb) ^ ((ra & 7) << 4)));
      int rb = tj * 16 + fr;
      bf16x8 bf_ = *(const bf16x8*)(Kl + rb * 128 + ((k0 * 64 + fkb) ^ ((rb & 7) << 4)));
      a4 = mfma16(af, bf_, a4);
    }
#pragma unroll
    for (int r = 0; r < 4; ++r)
      S[(ti * 16 + ((lane >> 4) << 2) + r) * 81 + tj * 16 + (lane & 15)] = a4[r];
  }
  __syncthreads();

  // add mask (coalesced)
  const float* mb = mask + (size_t)b * 4624;
  for (int e = tid; e < 4624; e += 256) {
    int i = e / 68, j = e - i * 68;
    S[i * 81 + j] += mb[e];
  }
  __syncthreads();

  // row softmax (threads 0..67), write P bf16 (stride 192, 2-bit swizzle) over Q region
  if (tid < 68) {
    float mx = -1e30f;
    for (int j = 0; j < 68; ++j) mx = fmaxf(mx, S[tid * 81 + j]);
    float sum = 0.f;
    for (int j = 0; j < 68; ++j) {
      float p = __expf(S[tid * 81 + j] - mx);
      S[tid * 81 + j] = p;
      sum += p;
    }
    float inv = 1.0f / sum;
    int swz = (tid & 3) << 4;
    for (int j = 0; j < 68; ++j)
      *(__bf16*)(Pq + tid * 192 + ((2 * j) ^ swz)) = (__bf16)(S[tid * 81 + j] * inv);
    for (int j = 68; j < 96; ++j)
      *(__bf16*)(Pq + tid * 192 + ((2 * j) ^ swz)) = (__bf16)0.f;
  }
  __syncthreads();

  // O = P @ V : 5x4 tiles, K=96 -> 3 steps (P cols/V rows >=68 are zero)
  for (int t = w; t < 20; t += 4) {
    int ti = t >> 2, td = t & 3;
    f32x4 a4 = (f32x4){0.f, 0.f, 0.f, 0.f};
#pragma unroll
    for (int k0 = 0; k0 < 3; ++k0) {
      int ra = ti * 16 + fr;
      bf16x8 af = *(const bf16x8*)(Pq + ra * 192 + ((k0 * 64 + fkb) ^ ((ra & 3) << 4)));
      int rb = td * 16 + fr;
      bf16x8 bf_ = *(const bf16x8*)(Vt + rb * 192 + ((k0 * 64 + fkb) ^ ((rb & 3) << 4)));
      a4 = mfma16(af, bf_, a4);
    }
#pragma unroll
    for (int r = 0; r < 4; ++r) {
      int i = ti * 16 + ((lane >> 4) << 2) + r;
      if (i < 68)
        ao[((size_t)(b * 68 + i)) * 768 + h * 64 + td * 16 + (lane & 15)] =
            __float2bfloat16(a4[r]);
    }
  }
}

// ---------------- launch ----------------
extern "C" void kernel_launch(void* const* d_in, const int* in_sizes, int n_in,
                              void* d_out, int out_size, void* d_ws, size_t ws_size,
                              hipStream_t stream) {
  const float* x     = (const float*)d_in[0];
  const float* pe    = (const float*)d_in[1];
  const float* mask  = (const float*)d_in[2];
  const float* wqkv  = (const float*)d_in[3];
  const float* bqkv  = (const float*)d_in[4];
  const float* wproj = (const float*)d_in[5];
  const float* bproj = (const float*)d_in[6];
  float* out = (float*)d_out;

  char* ws = (char*)d_ws;
  const size_t SZ = 106954752;  // 69632*768*2 bytes
  __hip_bfloat16* xb  = (__hip_bfloat16*)(ws);            // also attention output (A of proj)
  __hip_bfloat16* qb  = (__hip_bfloat16*)(ws + SZ);
  __hip_bfloat16* kb  = (__hip_bfloat16*)(ws + 2 * SZ);
  __hip_bfloat16* vb  = (__hip_bfloat16*)(ws + 3 * SZ);
  __hip_bfloat16* wqb = (__hip_bfloat16*)(ws + 4 * SZ);
  __hip_bfloat16* wpb = (__hip_bfloat16*)(ws + 4 * SZ + 3538944);

  // weights -> bf16
  cvt_bf16<<<1728, 256, 0, stream>>>(wqkv, wqb, 442368);   // 2304*768/4
  cvt_bf16<<<576, 256, 0, stream>>>(wproj, wpb, 147456);   // 768*768/4
  // x + pe -> bf16
  prep_x<<<52224, 256, 0, stream>>>(x, pe, xb);
  // QKV projection (scale folded into q)
  gemm_bt<0><<<dim3(18, 544), 256, 0, stream>>>(xb, wqb, bqkv, qb, kb, vb, nullptr, KDIM);
  // attention per (b,h)
  attn<<<12288, 256, 0, stream>>>(qb, kb, vb, mask, xb);
  // output projection -> f32
  gemm_bt<1><<<dim3(6, 544), 256, 0, stream>>>(xb, wpb, bproj, nullptr, nullptr, nullptr, out, KDIM);
}

// Round 5
// 1153.106 us; speedup vs baseline: 1.1583x; 1.1583x over previous
//
#include <hip/hip_runtime.h>
#include <hip/hip_bf16.h>
#include <stdint.h>

// Problem constants (B=1024, N=68, C=768, H=12, hd=64)
static constexpr int KDIM = 768;

typedef float  f32x4  __attribute__((ext_vector_type(4)));
typedef __bf16 bf16x8 __attribute__((ext_vector_type(8)));

__device__ __forceinline__ f32x4 mfma16(bf16x8 a, bf16x8 b, f32x4 c) {
  return __builtin_amdgcn_mfma_f32_16x16x32_bf16(a, b, c, 0, 0, 0);
}

__device__ __forceinline__ void async_ld16(void* lds, const void* g) {
  __builtin_amdgcn_global_load_lds((const __attribute__((address_space(1))) void*)g,
                                   (__attribute__((address_space(3))) void*)lds,
                                   16, 0, 0);
}

__device__ __forceinline__ void store4bf16(__hip_bfloat16* dst, f32x4 v) {
  __hip_bfloat16 tmp[4];
  tmp[0] = __float2bfloat16(v[0]);
  tmp[1] = __float2bfloat16(v[1]);
  tmp[2] = __float2bfloat16(v[2]);
  tmp[3] = __float2bfloat16(v[3]);
  *(uint2*)dst = *(const uint2*)tmp;
}

// ---------------- prep: f32 -> bf16 weight convert ----------------
__global__ __launch_bounds__(256) void cvt_bf16(const float* __restrict__ src,
                                                __hip_bfloat16* __restrict__ dst, int n4) {
  int i = blockIdx.x * 256 + threadIdx.x;
  if (i >= n4) return;
  f32x4 v = ((const f32x4*)src)[i];
  store4bf16(dst + (size_t)i * 4, v);
}

// ---------------- prep: xb = bf16(x + pe_crop) ----------------
__global__ __launch_bounds__(256) void prep_x(const float* __restrict__ x,
                                              const float* __restrict__ pe,
                                              __hip_bfloat16* __restrict__ xb) {
  int i = blockIdx.x * 256 + threadIdx.x;   // < 13,369,344 (exact grid)
  int m  = i / 192;
  int c4 = i - m * 192;
  int n  = m % 68;
  f32x4 v = ((const f32x4*)x)[i];
  if (n >= 4) {
    f32x4 p = ((const f32x4*)pe)[(n + 28) * 192 + c4];  // pe row = n + 28
    v[0] += p[0]; v[1] += p[1]; v[2] += p[2]; v[3] += p[3];
  }
  store4bf16(xb + (size_t)i * 4, v);
}

// ---------------- GEMM: C[m,j] = sum_k A[m,k]*B[j,k] + bias[j] ----------------
// 128x128 tile, BK=64, 4 waves. XOR-swizzled LDS + pre-swizzled global source
// for global_load_lds. 1-D grid with bijective XCD swizzle (nwg % 8 == 0).
// EPI=0: scatter to q/k/v bf16 (q scaled by 0.125); EPI=1: f32 out + bias.
template<int EPI>
__global__ __launch_bounds__(256)
void gemm_bt(const __hip_bfloat16* __restrict__ A,
             const __hip_bfloat16* __restrict__ Bm,
             const float* __restrict__ bias,
             __hip_bfloat16* __restrict__ qo,
             __hip_bfloat16* __restrict__ ko,
             __hip_bfloat16* __restrict__ vo,
             float* __restrict__ out,
             int K, int nbx) {
  __shared__ __align__(16) char lds[32768];
  char* lA = lds;
  char* lB = lds + 16384;

  const int tid  = threadIdx.x;
  const int w    = tid >> 6;
  const int lane = tid & 63;

  // XCD-aware bijective swizzle: consecutive swz-ids (same A-panel) on one XCD
  const int id  = blockIdx.x;
  const int swz = (id & 7) * ((int)gridDim.x >> 3) + (id >> 3);
  const int by  = swz / nbx;
  const int bx  = swz - by * nbx;
  const int m0 = by * 128;
  const int n0 = bx * 128;

  const int lrow = lane >> 3, slot = lane & 7;
  const size_t ldb = (size_t)K * 2;  // row stride bytes

  f32x4 acc[4][4];
#pragma unroll
  for (int i = 0; i < 4; ++i)
#pragma unroll
    for (int j = 0; j < 4; ++j) acc[i][j] = (f32x4){0.f, 0.f, 0.f, 0.f};

  const int wr = w >> 1, wc = w & 1;
  const int fr = lane & 15, fkb = (lane >> 4) << 4;

  const char* Ab = (const char*)A;
  const char* Bb = (const char*)Bm;

  for (int kt = 0; kt < K; kt += 64) {
#pragma unroll
    for (int c2 = 0; c2 < 4; ++c2) {
      int rb = c2 * 32 + w * 8;       // 8 rows per wave-call
      int r  = rb + lrow;
      int sk = (slot ^ (r & 7)) << 4; // pre-swizzled source k-slot
      async_ld16(lA + rb * 128, Ab + (size_t)(m0 + r) * ldb + (size_t)kt * 2 + sk);
      async_ld16(lB + rb * 128, Bb + (size_t)(n0 + r) * ldb + (size_t)kt * 2 + sk);
    }
    __syncthreads();
#pragma unroll
    for (int k0 = 0; k0 < 2; ++k0) {
      bf16x8 af[4], bfv[4];
#pragma unroll
      for (int i = 0; i < 4; ++i) {
        int ra = wr * 64 + i * 16 + fr;
        af[i] = *(const bf16x8*)(lA + ra * 128 + ((k0 * 64 + fkb) ^ ((ra & 7) << 4)));
        int rbB = wc * 64 + i * 16 + fr;
        bfv[i] = *(const bf16x8*)(lB + rbB * 128 + ((k0 * 64 + fkb) ^ ((rbB & 7) << 4)));
      }
#pragma unroll
      for (int i = 0; i < 4; ++i)
#pragma unroll
        for (int j = 0; j < 4; ++j)
          acc[i][j] = mfma16(af[i], bfv[j], acc[i][j]);
    }
    __syncthreads();
  }

  // epilogue: C/D layout col = lane&15, row = (lane>>4)*4 + r
  // hoisted per-j column info (block never crosses a q/k/v segment boundary)
  float bj[4];
  int hj[4], dj[4];
  const int which = (EPI == 0) ? (n0 >= 1536 ? 2 : (n0 >= 768 ? 1 : 0)) : 0;
#pragma unroll
  for (int j = 0; j < 4; ++j) {
    int jc = wc * 64 + j * 16 + (lane & 15);
    bj[j] = bias[n0 + jc];
    int jl = (n0 - which * 768) + jc;
    hj[j] = jl >> 6;
    dj[j] = jl & 63;
  }
  __hip_bfloat16* dst = (EPI == 0) ? (which == 0 ? qo : (which == 1 ? ko : vo)) : nullptr;
  const float scl = (EPI == 0 && which == 0) ? 0.125f : 1.0f;

#pragma unroll
  for (int i = 0; i < 4; ++i) {
#pragma unroll
    for (int r = 0; r < 4; ++r) {
      int m = m0 + wr * 64 + i * 16 + ((lane >> 4) << 2) + r;
      if (EPI == 0) {
        int bb = m / 68, n = m - bb * 68;
        size_t base = (size_t)bb * 12 * 4352 + (size_t)n * 64;
#pragma unroll
        for (int j = 0; j < 4; ++j)
          dst[base + (size_t)hj[j] * 4352 + dj[j]] =
              __float2bfloat16((acc[i][j][r] + bj[j]) * scl);
      } else {
#pragma unroll
        for (int j = 0; j < 4; ++j)
          out[(size_t)m * 768 + n0 + wc * 64 + j * 16 + (lane & 15)] = acc[i][j][r] + bj[j];
      }
    }
  }
}

// ---------------- attention: one block per (b,h) ----------------
// LDS: Pq (Q[68][64] bf16 then P[80][str192]), K[68][64] bf16, Vt[64][str192],
// S[80][84] f32, Sinv[80] f32. Rows/cols >= 68 in S are garbage but unused.
__global__ __launch_bounds__(256)
void attn(const __hip_bfloat16* __restrict__ q,
          const __hip_bfloat16* __restrict__ kk,
          const __hip_bfloat16* __restrict__ vv,
          const float* __restrict__ mask,
          __hip_bfloat16* __restrict__ ao) {
  __shared__ __align__(16) char sm[65088];
  char*  Pq = sm;                    // 15360
  char*  Kl = sm + 15360;            // 10240
  char*  Vt = sm + 25600;            // 12288
  float* S  = (float*)(sm + 37888);  // 80*84*4 = 26880
  float* Si = (float*)(sm + 64768);  // 80*4

  const int tid  = threadIdx.x;
  const int w    = tid >> 6;
  const int lane = tid & 63;
  // XCD swizzle: 12 heads of one batch contiguous on one XCD (mask L2 reuse)
  const int bid = blockIdx.x;
  const int bh  = (bid & 7) * 1536 + (bid >> 3);
  const int b = bh / 12, h = bh - b * 12;

  const __hip_bfloat16* qg = q  + (size_t)bh * 4352;
  const __hip_bfloat16* kg = kk + (size_t)bh * 4352;
  const __hip_bfloat16* vg = vv + (size_t)bh * 4352;

  // stage Q, K (row stride 128B, 3-bit XOR swizzle)
  for (int e = tid; e < 544; e += 256) {
    int row = e >> 3, slot = e & 7;
    int off = row * 128 + ((slot << 4) ^ ((row & 7) << 4));
    *(bf16x8*)(Pq + off) = *(const bf16x8*)(qg + e * 8);
    *(bf16x8*)(Kl + off) = *(const bf16x8*)(kg + e * 8);
  }
  // stage V transposed: Vt[d][j], row stride 192B, 2-bit XOR swizzle
  for (int e = tid; e < 544; e += 256) {
    int j = e >> 3, d8 = e & 7;
    bf16x8 vx = *(const bf16x8*)(vg + e * 8);
#pragma unroll
    for (int u = 0; u < 8; ++u) {
      int d = d8 * 8 + u;
      *(__bf16*)(Vt + d * 192 + ((2 * j) ^ ((d & 3) << 4))) = vx[u];
    }
  }
  // zero Vt pad cols 68..95 (guards 0*inf -> NaN from LDS garbage)
  for (int e = tid; e < 1792; e += 256) {
    int d = e / 28, j = 68 + e - d * 28;
    *(__bf16*)(Vt + d * 192 + ((2 * j) ^ ((d & 3) << 4))) = (__bf16)0.f;
  }
  __syncthreads();

  const int fr = lane & 15, fkb = (lane >> 4) << 4;

  // S = Q @ K^T over 5x5 tiles of 16x16 (K=64 -> 2 steps)
  for (int t = w; t < 25; t += 4) {
    int ti = t / 5, tj = t - ti * 5;
    f32x4 a4 = (f32x4){0.f, 0.f, 0.f, 0.f};
#pragma unroll
    for (int k0 = 0; k0 < 2; ++k0) {
      int ra = ti * 16 + fr;
      bf16x8 af = *(const bf16x8*)(Pq + ra * 128 + ((k0 * 64 + fkb) ^ ((ra & 7) << 4)));
      int rb = tj * 16 + fr;
      bf16x8 bf_ = *(const bf16x8*)(Kl + rb * 128 + ((k0 * 64 + fkb) ^ ((rb & 7) << 4)));
      a4 = mfma16(af, bf_, a4);
    }
#pragma unroll
    for (int r = 0; r < 4; ++r)
      S[(ti * 16 + ((lane >> 4) << 2) + r) * 84 + tj * 16 + (lane & 15)] = a4[r];
  }
  __syncthreads();

  // add mask (coalesced read)
  const float* mb = mask + (size_t)b * 4624;
  for (int e = tid; e < 4624; e += 256) {
    int i = e / 68, j = e - i * 68;
    S[i * 84 + j] += mb[e];
  }
  __syncthreads();

  // row softmax, vectorized f32x4 (68 cols = 17 exact vecs). P stored
  // UNNORMALIZED bf16; 1/sum applied in the PV epilogue.
  if (tid < 68) {
    const f32x4* Srow = (const f32x4*)(S + tid * 84);
    f32x4 m4 = Srow[0];
#pragma unroll
    for (int i = 1; i < 17; ++i) {
      f32x4 v = Srow[i];
      m4[0] = fmaxf(m4[0], v[0]); m4[1] = fmaxf(m4[1], v[1]);
      m4[2] = fmaxf(m4[2], v[2]); m4[3] = fmaxf(m4[3], v[3]);
    }
    float mx = fmaxf(fmaxf(m4[0], m4[1]), fmaxf(m4[2], m4[3]));
    float sum = 0.f;
    char* Prow = Pq + tid * 192;
    const int swzb = (tid & 3) << 4;
#pragma unroll
    for (int ib = 0; ib < 12; ++ib) {
      bf16x8 pk;
      if (ib < 8) {
        f32x4 a = Srow[2 * ib], c = Srow[2 * ib + 1];
#pragma unroll
        for (int u = 0; u < 4; ++u) {
          float pa = __expf(a[u] - mx), pc = __expf(c[u] - mx);
          sum += pa + pc;
          pk[u] = (__bf16)pa; pk[4 + u] = (__bf16)pc;
        }
      } else if (ib == 8) {
        f32x4 a = Srow[16];
#pragma unroll
        for (int u = 0; u < 4; ++u) {
          float pa = __expf(a[u] - mx);
          sum += pa;
          pk[u] = (__bf16)pa; pk[4 + u] = (__bf16)0.f;
        }
      } else {
#pragma unroll
        for (int u = 0; u < 8; ++u) pk[u] = (__bf16)0.f;
      }
      *(bf16x8*)(Prow + ((ib * 16) ^ swzb)) = pk;
    }
    Si[tid] = 1.0f / sum;
  }
  __syncthreads();

  // O = P @ V : 5x4 tiles, K=96 -> 3 steps (P/Vt cols >= 68 are zero)
  for (int t = w; t < 20; t += 4) {
    int ti = t >> 2, td = t & 3;
    f32x4 a4 = (f32x4){0.f, 0.f, 0.f, 0.f};
#pragma unroll
    for (int k0 = 0; k0 < 3; ++k0) {
      int ra = ti * 16 + fr;
      bf16x8 af = *(const bf16x8*)(Pq + ra * 192 + ((k0 * 64 + fkb) ^ ((ra & 3) << 4)));
      int rb = td * 16 + fr;
      bf16x8 bf_ = *(const bf16x8*)(Vt + rb * 192 + ((k0 * 64 + fkb) ^ ((rb & 3) << 4)));
      a4 = mfma16(af, bf_, a4);
    }
#pragma unroll
    for (int r = 0; r < 4; ++r) {
      int i = ti * 16 + ((lane >> 4) << 2) + r;
      if (i < 68) {
        float inv = Si[i];
        ao[((size_t)(b * 68 + i)) * 768 + h * 64 + td * 16 + (lane & 15)] =
            __float2bfloat16(a4[r] * inv);
      }
    }
  }
}

// ---------------- launch ----------------
extern "C" void kernel_launch(void* const* d_in, const int* in_sizes, int n_in,
                              void* d_out, int out_size, void* d_ws, size_t ws_size,
                              hipStream_t stream) {
  const float* x     = (const float*)d_in[0];
  const float* pe    = (const float*)d_in[1];
  const float* mask  = (const float*)d_in[2];
  const float* wqkv  = (const float*)d_in[3];
  const float* bqkv  = (const float*)d_in[4];
  const float* wproj = (const float*)d_in[5];
  const float* bproj = (const float*)d_in[6];
  float* out = (float*)d_out;

  char* ws = (char*)d_ws;
  const size_t SZ = 106954752;  // 69632*768*2 bytes
  __hip_bfloat16* xb  = (__hip_bfloat16*)(ws);            // also attention output
  __hip_bfloat16* qb  = (__hip_bfloat16*)(ws + SZ);
  __hip_bfloat16* kb  = (__hip_bfloat16*)(ws + 2 * SZ);
  __hip_bfloat16* vb  = (__hip_bfloat16*)(ws + 3 * SZ);
  __hip_bfloat16* wqb = (__hip_bfloat16*)(ws + 4 * SZ);
  __hip_bfloat16* wpb = (__hip_bfloat16*)(ws + 4 * SZ + 3538944);

  cvt_bf16<<<1728, 256, 0, stream>>>(wqkv, wqb, 442368);   // 2304*768/4
  cvt_bf16<<<576, 256, 0, stream>>>(wproj, wpb, 147456);   // 768*768/4
  prep_x<<<52224, 256, 0, stream>>>(x, pe, xb);
  // QKV projection: 9792 blocks (18 x 544), scale folded into q
  gemm_bt<0><<<9792, 256, 0, stream>>>(xb, wqb, bqkv, qb, kb, vb, nullptr, KDIM, 18);
  // attention per (b,h)
  attn<<<12288, 256, 0, stream>>>(qb, kb, vb, mask, xb);
  // output projection -> f32: 3264 blocks (6 x 544)
  gemm_bt<1><<<3264, 256, 0, stream>>>(xb, wpb, bproj, nullptr, nullptr, nullptr, out, KDIM, 6);
}